// Round 6
// baseline (347.044 us; speedup 1.0000x reference)
//
#include <hip/hip_runtime.h>
#include <hip/hip_bf16.h>
#include <cstdint>

typedef __hip_bfloat16 BF;
typedef unsigned short ushort_t;
typedef __attribute__((ext_vector_type(8))) __bf16 bf16x8;
typedef __attribute__((ext_vector_type(4))) float f32x4;

__device__ __forceinline__ float b2f(BF x) { return __bfloat162float(x); }
__device__ __forceinline__ unsigned short f2bu(float f) {
  union { BF b; unsigned short u; } c; c.b = __float2bfloat16(f); return c.u;
}
__device__ __forceinline__ float rdE(const void* p, size_t i, bool f32) {
  return f32 ? ((const float*)p)[i] : __bfloat162float(((const BF*)p)[i]);
}
// Read 16 consecutive external elements as bf16 bit patterns.
__device__ __forceinline__ void rd16(const void* p, size_t i, bool f32, ushort_t* out) {
  if (f32) {
    const float* fp = (const float*)p + i;
#pragma unroll
    for (int j = 0; j < 16; j += 4) {
      float4 v = *(const float4*)(fp + j);
      out[j] = f2bu(v.x); out[j + 1] = f2bu(v.y);
      out[j + 2] = f2bu(v.z); out[j + 3] = f2bu(v.w);
    }
  } else {
    const uint4* up = (const uint4*)((const BF*)p + i);
    *(uint4*)&out[0] = up[0];
    *(uint4*)&out[8] = up[1];
  }
}

// Detect input dtype (fp32 vs bf16) from bit patterns; see round-1 notes.
__global__ void detect_k(const unsigned short* __restrict__ x, int* __restrict__ flag) {
  __shared__ int cnt;
  if (threadIdx.x == 0) cnt = 0;
  __syncthreads();
  int c = 0;
  for (int i = threadIdx.x; i < 4096; i += 256) {
    int e = (x[i] >> 7) & 0xFF;
    if (e >= 0x86) c++;
  }
  if (c) atomicAdd(&cnt, c);
  __syncthreads();
  if (threadIdx.x == 0) *flag = (cnt > 64) ? 1 : 0;
}

// ---------------------------------------------------------------------------
// MFMA GEMM: C = A @ B^T (+bias epilogues). 128x128 tile, 4 waves x 64x64.
// MODE 0: Q proj (A=local row-maj)  -> RoPE(local)  -> bf16 Q[b,h,q,dh]
// MODE 5: fused K/V proj (A=gfeat col-maj, staged once):
//         blockIdx.y<4 -> K + RoPE(global) -> Kb; else V -> V^T (LDS bounce)
// MODE 3: gate  (A=[local|AO] K=1024) -> sigmoid gate -> ENH bf16
// MODE 4: out   (A=ENH bf16)         -> bias          -> external d_out
// ---------------------------------------------------------------------------
template <int MODE>
__global__ __launch_bounds__(256) void mgemm_k(
    const void* __restrict__ Aext, const BF* __restrict__ Aint,
    const void* __restrict__ Bw, const void* __restrict__ Bw2,
    const void* __restrict__ biasv, const void* __restrict__ bias2,
    BF* __restrict__ outInt, BF* __restrict__ outInt2,
    void* __restrict__ outExt, int Kdim, const int* __restrict__ flagp) {
  const bool f32 = (*flagp != 0);
  __shared__ __align__(16) ushort_t smem[2][128][72];
  auto As = smem[0];
  auto Bs = smem[1];
  const int tid = threadIdx.x;
  const int w = tid >> 6, lane = tid & 63;
  const int quad = lane >> 4, l16 = lane & 15;
  const int wm = w >> 1, wn = w & 1;
  const int m0 = blockIdx.x * 128, n0 = blockIdx.y * 128;
  const int bz = blockIdx.z;

  f32x4 acc[4][4] = {};

  for (int k0 = 0; k0 < Kdim; k0 += 64) {
    __syncthreads();
    if constexpr (MODE == 5) {
      // col-major: element (m,k) at bz*512*4096 + k*4096 + m; transpose in LDS
#pragma unroll
      for (int u = 0; u < 2; ++u) {
        int unit = tid + u * 256;          // 512 units: 64 k x 8 m-groups
        int k = unit >> 3, mg = unit & 7;
        int ksw = k ^ (8 * (mg & 3));      // bank-conflict swizzle
        size_t base = (size_t)bz * 512 * 4096 + (size_t)(k0 + k) * 4096 + m0 + mg * 16;
        ushort_t vals[16];
        rd16(Aext, base, f32, vals);
#pragma unroll
        for (int j = 0; j < 16; ++j) As[mg * 16 + j][ksw] = vals[j];
      }
    } else {
#pragma unroll
      for (int u = 0; u < 2; ++u) {
        int unit = tid + u * 256;          // 512 units: 128 rows x 4 col-groups
        int row = unit >> 2, cg = unit & 3;
        int kg = k0 + cg * 16;
        ushort_t vals[16];
        if constexpr (MODE == 3) {
          if (kg < 512) {
            rd16(Aext, (size_t)(m0 + row) * 512 + kg, f32, vals);
          } else {
            const uint4* p = (const uint4*)(Aint + (size_t)(m0 + row) * 512 + (kg - 512));
            *(uint4*)&vals[0] = p[0]; *(uint4*)&vals[8] = p[1];
          }
        } else if constexpr (MODE == 4) {
          const uint4* p = (const uint4*)(Aint + (size_t)(m0 + row) * 512 + kg);
          *(uint4*)&vals[0] = p[0]; *(uint4*)&vals[8] = p[1];
        } else {  // MODE 0
          rd16(Aext, (size_t)(m0 + row) * Kdim + kg, f32, vals);
        }
        *(uint4*)&As[row][cg * 16] = *(uint4*)&vals[0];
        *(uint4*)&As[row][cg * 16 + 8] = *(uint4*)&vals[8];
      }
    }
    // ---- stage B tile (128 n x 64 k); W is (N,K) row-major ----
#pragma unroll
    for (int u = 0; u < 2; ++u) {
      int unit = tid + u * 256;
      int row = unit >> 2, cg = unit & 3;
      const void* bsrc = Bw;
      size_t nrow = n0 + row;
      if constexpr (MODE == 5) {
        if (n0 >= 512) { bsrc = Bw2; nrow -= 512; }
      }
      ushort_t vals[16];
      rd16(bsrc, nrow * Kdim + k0 + cg * 16, f32, vals);
      *(uint4*)&Bs[row][cg * 16] = *(uint4*)&vals[0];
      *(uint4*)&Bs[row][cg * 16 + 8] = *(uint4*)&vals[8];
    }
    __syncthreads();
#pragma unroll
    for (int kc = 0; kc < 2; ++kc) {
      bf16x8 af[4], bfv[4];
#pragma unroll
      for (int i = 0; i < 4; ++i) {
        int col = kc * 32 + quad * 8;
        if constexpr (MODE == 5) col ^= 8 * (i & 3);
        af[i] = *(const bf16x8*)&As[wm * 64 + i * 16 + l16][col];
        bfv[i] = *(const bf16x8*)&Bs[wn * 64 + i * 16 + l16][kc * 32 + quad * 8];
      }
#pragma unroll
      for (int mt = 0; mt < 4; ++mt)
#pragma unroll
        for (int nt = 0; nt < 4; ++nt)
          acc[mt][nt] = __builtin_amdgcn_mfma_f32_16x16x32_bf16(af[mt], bfv[nt], acc[mt][nt], 0, 0, 0);
    }
  }

  if constexpr (MODE == 0) {
    const int head = (n0 + wn * 64) >> 6;
#pragma unroll
    for (int mt = 0; mt < 4; ++mt)
#pragma unroll
      for (int r = 0; r < 4; ++r) {
        int mg = m0 + wm * 64 + mt * 16 + quad * 4 + r;
        int bb = mg >> 10, qi = mg & 1023;
        float x = (float)(qi & 31) * (1.f / 31.f);
        float y = (float)(qi >> 5) * (1.f / 31.f);
        size_t base = (((size_t)bb * 8 + head) * 1024 + qi) * 64;
#pragma unroll
        for (int j = 0; j < 2; ++j) {
          int c0 = j * 16 + l16;
          float t0 = acc[mt][j][r] + rdE(biasv, head * 64 + c0, f32);
          float t1 = acc[mt][j + 2][r] + rdE(biasv, head * 64 + c0 + 32, f32);
          float fr = __expf((float)c0 * (-9.210340371976184f / 32.f));
          float ax = x * fr, ay = y * fr;
          outInt[base + c0] = __float2bfloat16(t0 * __cosf(ax) - t1 * __sinf(ax));
          outInt[base + c0 + 32] = __float2bfloat16(t1 * __cosf(ay) + t0 * __sinf(ay));
        }
      }
  } else if constexpr (MODE == 5) {
    if (n0 < 512) {  // ---- K + RoPE(global coords) ----
      const int head = (n0 + wn * 64) >> 6;
#pragma unroll
      for (int mt = 0; mt < 4; ++mt)
#pragma unroll
        for (int r = 0; r < 4; ++r) {
          int pg = m0 + wm * 64 + mt * 16 + quad * 4 + r;
          float x = (float)(pg & 63) * (1.f / 63.f);
          float y = (float)(pg >> 6) * (1.f / 63.f);
          size_t base = (((size_t)bz * 8 + head) * 4096 + pg) * 64;
#pragma unroll
          for (int j = 0; j < 2; ++j) {
            int c0 = j * 16 + l16;
            float t0 = acc[mt][j][r] + rdE(biasv, head * 64 + c0, f32);
            float t1 = acc[mt][j + 2][r] + rdE(biasv, head * 64 + c0 + 32, f32);
            float fr = __expf((float)c0 * (-9.210340371976184f / 32.f));
            float ax = x * fr, ay = y * fr;
            outInt[base + c0] = __float2bfloat16(t0 * __cosf(ax) - t1 * __sinf(ax));
            outInt[base + c0 + 32] = __float2bfloat16(t1 * __cosf(ay) + t0 * __sinf(ay));
          }
        }
    } else {  // ---- V -> V^T[b,h,dh,key] via LDS-bounce transpose ----
      const int n0v = n0 - 512;
      __syncthreads();  // all waves done with As/Bs frag reads
      ushort_t (*T)[136] = (ushort_t(*)[136]) & smem[0][0][0];  // 128x136 fits
#pragma unroll
      for (int mt = 0; mt < 4; ++mt)
#pragma unroll
        for (int nt = 0; nt < 4; ++nt)
#pragma unroll
          for (int r = 0; r < 4; ++r) {
            int n_l = wn * 64 + nt * 16 + l16;
            int m_l = wm * 64 + mt * 16 + quad * 4 + r;
            T[n_l][m_l] = f2bu(acc[mt][nt][r] + rdE(bias2, n0v + n_l, f32));
          }
      __syncthreads();
      int row = tid >> 1, half = tid & 1;  // row = local dh 0..127
      size_t gbase = (((size_t)bz * 8 + (n0v >> 6) + (row >> 6)) * 64 + (row & 63)) * 4096 +
                     m0 + half * 64;
      uint4* dst = (uint4*)(outInt2 + gbase);
      const uint4* src = (const uint4*)&T[row][half * 64];
#pragma unroll
      for (int j = 0; j < 8; ++j) dst[j] = src[j];
    }
  } else if constexpr (MODE == 3) {
#pragma unroll
    for (int mt = 0; mt < 4; ++mt)
#pragma unroll
      for (int r = 0; r < 4; ++r) {
        int mg = m0 + wm * 64 + mt * 16 + quad * 4 + r;
#pragma unroll
        for (int nt = 0; nt < 4; ++nt) {
          int ng = n0 + wn * 64 + nt * 16 + l16;
          size_t idx = (size_t)mg * 512 + ng;
          float g = 1.f / (1.f + __expf(-(acc[mt][nt][r] + rdE(biasv, ng, f32))));
          outInt[idx] = __float2bfloat16(rdE(Aext, idx, f32) + g * b2f(Aint[idx]));
        }
      }
  } else {  // MODE 4
#pragma unroll
    for (int mt = 0; mt < 4; ++mt)
#pragma unroll
      for (int r = 0; r < 4; ++r) {
        int mg = m0 + wm * 64 + mt * 16 + quad * 4 + r;
#pragma unroll
        for (int nt = 0; nt < 4; ++nt) {
          int ng = n0 + wn * 64 + nt * 16 + l16;
          size_t idx = (size_t)mg * 512 + ng;
          float v = acc[mt][nt][r] + rdE(biasv, ng, f32);
          if (f32) ((float*)outExt)[idx] = v;
          else ((BF*)outExt)[idx] = __float2bfloat16(v);
        }
      }
  }
}

// ---------------------------------------------------------------------------
// MFMA flash attention v3.
//  - bh-minor block mapping: XCD = blockIdx%8 = bh%8 -> per-XCD K/V working
//    set = 4 bh x 1 MB = 4 MB (fits per-XCD L2); was 32 MB (4x over-fetch).
//  - Ps XOR swizzle (col ^= 8*quad write-side) -> 2-way banks (free).
//  - exp2-folded scale: Q pre-scaled by 0.125*log2(e), p = exp2(s).
//  - NS=2: keys split across 2 blocks; partials (O bf16, l f32) merged by
//    reduce_k. m=0 softmax makes the merge a plain add.
// ---------------------------------------------------------------------------
template <int NS>
__global__ __launch_bounds__(256) void attn_k(const BF* __restrict__ Q,
                                              const BF* __restrict__ K,
                                              const BF* __restrict__ VT,
                                              BF* __restrict__ AO,
                                              BF* __restrict__ Opart,
                                              float* __restrict__ lpart) {
  __shared__ __align__(16) ushort_t Ks[64][72];
  __shared__ __align__(16) ushort_t VTs[64][72];
  __shared__ __align__(16) ushort_t Ps[4][16][72];

  const int tid = threadIdx.x;
  const int w = tid >> 6, lane = tid & 63;
  const int quad = lane >> 4, l16 = lane & 15;

  const int bh = blockIdx.x & 31;               // XCD = bh % 8
  const int qt = (blockIdx.x >> 5) & 15;
  const int ks = (NS == 2) ? (blockIdx.x >> 9) : 0;
  const int b = bh >> 3, h = bh & 7;
  const int q0 = qt * 64 + w * 16;
  const int kbase = ks * (4096 / NS);
  const int kspan = 4096 / NS;

  bf16x8 qa[2];
  {
    const BF* qp = Q + (((size_t)bh << 10) + q0 + l16) * 64 + quad * 8;
#pragma unroll
    for (int hh = 0; hh < 2; ++hh) {
      bf16x8 t = *(const bf16x8*)(qp + 32 * hh);
#pragma unroll
      for (int j = 0; j < 8; ++j) t[j] = (__bf16)(0.1803368801111f * (float)t[j]);
      qa[hh] = t;  // scale = (1/8)*log2(e); p = exp2(s)
    }
  }

  const BF* Kp = K + (size_t)bh * 4096 * 64;    // [key][dh]
  const BF* VTp = VT + (size_t)bh * 64 * 4096;  // [dh][key]

  f32x4 o[4] = {};
  float lp[4] = {};

  const int srow = tid >> 2, scol = (tid & 3) * 16;
  const int pcol = (quad * 8) ^ (8 * (l16 >> 2));  // swizzled P read col
  {  // stage first chunk
    const uint4* kp = (const uint4*)(Kp + (size_t)(kbase + srow) * 64 + scol);
    const uint4* vp = (const uint4*)(VTp + (size_t)srow * 4096 + kbase + scol);
    uint4 a = kp[0], bv = kp[1], c = vp[0], d = vp[1];
    *(uint4*)&Ks[srow][scol] = a;  *(uint4*)&Ks[srow][scol + 8] = bv;
    *(uint4*)&VTs[srow][scol] = c; *(uint4*)&VTs[srow][scol + 8] = d;
  }

  for (int c0 = kbase; c0 < kbase + kspan; c0 += 64) {
    __syncthreads();  // staged chunk visible
    uint4 nk0, nk1, nv0, nv1;
    const bool more = (c0 + 64 < kbase + kspan);
    if (more) {  // prefetch next chunk into registers
      const uint4* kp = (const uint4*)(Kp + (size_t)(c0 + 64 + srow) * 64 + scol);
      const uint4* vp = (const uint4*)(VTp + (size_t)srow * 4096 + c0 + 64 + scol);
      nk0 = kp[0]; nk1 = kp[1]; nv0 = vp[0]; nv1 = vp[1];
    }

    // ---- S = Qs K^T ; P = exp2(S) (m=0 softmax) ----
    float p[4][4];
#pragma unroll
    for (int ct = 0; ct < 4; ++ct) {
      f32x4 s = {};
      bf16x8 kb0 = *(const bf16x8*)&Ks[ct * 16 + l16][quad * 8];
      bf16x8 kb1 = *(const bf16x8*)&Ks[ct * 16 + l16][32 + quad * 8];
      s = __builtin_amdgcn_mfma_f32_16x16x32_bf16(qa[0], kb0, s, 0, 0, 0);
      s = __builtin_amdgcn_mfma_f32_16x16x32_bf16(qa[1], kb1, s, 0, 0, 0);
#pragma unroll
      for (int r = 0; r < 4; ++r) p[ct][r] = __builtin_exp2f(s[r]);
    }
#pragma unroll
    for (int r = 0; r < 4; ++r) lp[r] += (p[0][r] + p[1][r]) + (p[2][r] + p[3][r]);

    // ---- P: C-layout -> per-wave LDS (XOR-swizzled) -> A-layout ----
#pragma unroll
    for (int ct = 0; ct < 4; ++ct)
#pragma unroll
      for (int r = 0; r < 4; ++r)
        Ps[w][quad * 4 + r][(ct * 16 + l16) ^ (8 * quad)] = f2bu(p[ct][r]);
    bf16x8 pa0 = *(const bf16x8*)&Ps[w][l16][pcol];
    bf16x8 pa1 = *(const bf16x8*)&Ps[w][l16][32 + pcol];

    // ---- O += P V ----
#pragma unroll
    for (int nt = 0; nt < 4; ++nt) {
      bf16x8 vb0 = *(const bf16x8*)&VTs[nt * 16 + l16][quad * 8];
      bf16x8 vb1 = *(const bf16x8*)&VTs[nt * 16 + l16][32 + quad * 8];
      o[nt] = __builtin_amdgcn_mfma_f32_16x16x32_bf16(pa0, vb0, o[nt], 0, 0, 0);
      o[nt] = __builtin_amdgcn_mfma_f32_16x16x32_bf16(pa1, vb1, o[nt], 0, 0, 0);
    }

    __syncthreads();  // all LDS reads of this chunk done
    if (more) {
      *(uint4*)&Ks[srow][scol] = nk0;  *(uint4*)&Ks[srow][scol + 8] = nk1;
      *(uint4*)&VTs[srow][scol] = nv0; *(uint4*)&VTs[srow][scol + 8] = nv1;
    }
  }

  float invl[4];
#pragma unroll
  for (int r = 0; r < 4; ++r) {
    float v = lp[r];
#pragma unroll
    for (int d = 1; d < 16; d <<= 1) v += __shfl_xor(v, d);
    if (NS == 1) invl[r] = 1.f / v;
    else if (l16 == 0)
      lpart[((size_t)(ks * 32 + bh) << 10) + q0 + quad * 4 + r] = v;
  }
#pragma unroll
  for (int nt = 0; nt < 4; ++nt)
#pragma unroll
    for (int r = 0; r < 4; ++r) {
      int qg = q0 + quad * 4 + r;
      if (NS == 1) {
        AO[(((size_t)b << 10) + qg) * 512 + h * 64 + nt * 16 + l16] =
            __float2bfloat16(o[nt][r] * invl[r]);
      } else {
        Opart[(((size_t)(ks * 32 + bh) << 10) + qg) * 64 + nt * 16 + l16] =
            __float2bfloat16(o[nt][r]);
      }
    }
}

// Merge the two K-split halves: AO = (Oa+Ob)/(la+lb).
__global__ __launch_bounds__(256) void reduce_k(const BF* __restrict__ Opart,
                                                const float* __restrict__ lpart,
                                                BF* __restrict__ AO) {
  int e0 = (blockIdx.x * 256 + threadIdx.x) * 4;  // 2M elems total
  int row = e0 >> 6, col = e0 & 63;
  const ushort_t* a = (const ushort_t*)Opart + (size_t)row * 64 + col;
  const ushort_t* c = a + (size_t)32 * 1024 * 64;
  float inv = 1.f / (lpart[row] + lpart[row + 32768]);
  uint2 ua = *(const uint2*)a, uc = *(const uint2*)c;
  const ushort_t* pa = (const ushort_t*)&ua;
  const ushort_t* pc = (const ushort_t*)&uc;
  ushort_t outv[4];
#pragma unroll
  for (int j = 0; j < 4; ++j) {
    float va = __uint_as_float((unsigned)pa[j] << 16);
    float vc = __uint_as_float((unsigned)pc[j] << 16);
    outv[j] = f2bu((va + vc) * inv);
  }
  int bh = row >> 10, q = row & 1023, bb = bh >> 3, h = bh & 7;
  *(uint2*)(AO + (((size_t)bb << 10) + q) * 512 + h * 64 + col) = *(uint2*)outv;
}

extern "C" void kernel_launch(void* const* d_in, const int* in_sizes, int n_in,
                              void* d_out, int out_size, void* d_ws, size_t ws_size,
                              hipStream_t stream) {
  const void* local = d_in[0];
  const void* gfeat = d_in[1];
  const void* Wq = d_in[2];
  const void* bq = d_in[3];
  const void* Wk = d_in[4];
  const void* bk = d_in[5];
  const void* Wv = d_in[6];
  const void* bv = d_in[7];
  const void* Wg = d_in[8];
  const void* bg = d_in[9];
  const void* Wo = d_in[10];
  const void* bo = d_in[11];

  char* w = (char*)d_ws;
  int* flag = (int*)w;        w += 256;
  BF* Qb = (BF*)w;            w += (size_t)2097152 * 2;  // 4 MB (reused as ENH)
  BF* Kb = (BF*)w;            w += (size_t)8388608 * 2;  // 16 MB
  BF* VTb = (BF*)w;           w += (size_t)8388608 * 2;  // 16 MB (V^T: [b,h,dh,key])
  BF* AO = (BF*)w;            w += (size_t)2097152 * 2;  // 4 MB
  BF* Opart = (BF*)w;         w += (size_t)4194304 * 2;  // 8 MB (2 x 4 MB partial O)
  float* lpart = (float*)w;   w += (size_t)65536 * 4;    // 256 KB partial l
  BF* ENH = Qb;

  const bool ksplit = ((size_t)(w - (char*)d_ws) <= ws_size);

  dim3 blk(256);
  detect_k<<<dim3(1), blk, 0, stream>>>((const unsigned short*)local, flag);
  mgemm_k<0><<<dim3(32, 4, 1), blk, 0, stream>>>(local, nullptr, Wq, nullptr, bq, nullptr, Qb, nullptr, nullptr, 512, flag);
  mgemm_k<5><<<dim3(32, 8, 4), blk, 0, stream>>>(gfeat, nullptr, Wk, Wv, bk, bv, Kb, VTb, nullptr, 512, flag);
  if (ksplit) {
    attn_k<2><<<dim3(1024), blk, 0, stream>>>(Qb, Kb, VTb, AO, Opart, lpart);
    reduce_k<<<dim3(2048), blk, 0, stream>>>(Opart, lpart, AO);
  } else {
    attn_k<1><<<dim3(512), blk, 0, stream>>>(Qb, Kb, VTb, AO, nullptr, nullptr);
  }
  mgemm_k<3><<<dim3(32, 4, 1), blk, 0, stream>>>(local, AO, Wg, nullptr, bg, nullptr, ENH, nullptr, nullptr, 1024, flag);
  mgemm_k<4><<<dim3(32, 4, 1), blk, 0, stream>>>(nullptr, ENH, Wo, nullptr, bo, nullptr, nullptr, nullptr, d_out, 512, flag);
}

// Round 7
// 293.699 us; speedup vs baseline: 1.1816x; 1.1816x over previous
//
#include <hip/hip_runtime.h>
#include <hip/hip_bf16.h>
#include <cstdint>

typedef __hip_bfloat16 BF;
typedef unsigned short ushort_t;
typedef __attribute__((ext_vector_type(8))) __bf16 bf16x8;
typedef __attribute__((ext_vector_type(4))) float f32x4;

__device__ __forceinline__ float b2f(BF x) { return __bfloat162float(x); }
__device__ __forceinline__ unsigned short f2bu(float f) {
  union { BF b; unsigned short u; } c; c.b = __float2bfloat16(f); return c.u;
}
__device__ __forceinline__ float rdE(const void* p, size_t i, bool f32) {
  return f32 ? ((const float*)p)[i] : __bfloat162float(((const BF*)p)[i]);
}
// Read 16 consecutive external elements as bf16 bit patterns.
__device__ __forceinline__ void rd16(const void* p, size_t i, bool f32, ushort_t* out) {
  if (f32) {
    const float* fp = (const float*)p + i;
#pragma unroll
    for (int j = 0; j < 16; j += 4) {
      float4 v = *(const float4*)(fp + j);
      out[j] = f2bu(v.x); out[j + 1] = f2bu(v.y);
      out[j + 2] = f2bu(v.z); out[j + 3] = f2bu(v.w);
    }
  } else {
    const uint4* up = (const uint4*)((const BF*)p + i);
    *(uint4*)&out[0] = up[0];
    *(uint4*)&out[8] = up[1];
  }
}

// Detect input dtype (fp32 vs bf16) from bit patterns; see round-1 notes.
__global__ void detect_k(const unsigned short* __restrict__ x, int* __restrict__ flag) {
  __shared__ int cnt;
  if (threadIdx.x == 0) cnt = 0;
  __syncthreads();
  int c = 0;
  for (int i = threadIdx.x; i < 4096; i += 256) {
    int e = (x[i] >> 7) & 0xFF;
    if (e >= 0x86) c++;
  }
  if (c) atomicAdd(&cnt, c);
  __syncthreads();
  if (threadIdx.x == 0) *flag = (cnt > 64) ? 1 : 0;
}

// ---------------------------------------------------------------------------
// MFMA GEMM, C = A @ B^T (+bias epilogues).
// MODE 0/3/4: 64x64 tile (grid 512 -> 2 blocks/CU; these are latency-bound),
//   4 waves each own a 16x64 strip.
// MODE 5: 128x128 tile, fused K/V proj, 1D grid with XCD-pinned A-tile reuse
//   (the 8 n-tiles sharing one (m,bz) A-tile have identical g&7 -> same XCD).
// ---------------------------------------------------------------------------
template <int MODE>
__global__ __launch_bounds__(256) void mgemm_k(
    const void* __restrict__ Aext, const BF* __restrict__ Aint,
    const void* __restrict__ Bw, const void* __restrict__ Bw2,
    const void* __restrict__ biasv, const void* __restrict__ bias2,
    BF* __restrict__ outInt, BF* __restrict__ outInt2,
    void* __restrict__ outExt, int Kdim, const int* __restrict__ flagp) {
  const bool f32 = (*flagp != 0);
  const int tid = threadIdx.x;
  const int w = tid >> 6, lane = tid & 63;
  const int quad = lane >> 4, l16 = lane & 15;

  if constexpr (MODE == 5) {
    __shared__ __align__(16) ushort_t smem[2][128][72];
    auto As = smem[0];
    auto Bs = smem[1];
    const int wm = w >> 1, wn = w & 1;
    // 1D grid decode: a=g&7 (XCD slot), y=(g>>3)&7, b=g>>6.
    const int g = blockIdx.x;
    const int a = g & 7, y = (g >> 3) & 7, bidx = g >> 6;
    const int m0 = ((bidx << 1) | (a & 1)) * 128;
    const int n0 = y * 128;
    const int bz = a >> 1;

    f32x4 acc[4][4] = {};
    for (int k0 = 0; k0 < Kdim; k0 += 64) {
      __syncthreads();
#pragma unroll
      for (int u = 0; u < 2; ++u) {  // A: col-major gfeat, transpose in LDS
        int unit = tid + u * 256;
        int k = unit >> 3, mg = unit & 7;
        int ksw = k ^ (8 * (mg & 3));
        size_t base = (size_t)bz * 512 * 4096 + (size_t)(k0 + k) * 4096 + m0 + mg * 16;
        ushort_t vals[16];
        rd16(Aext, base, f32, vals);
#pragma unroll
        for (int j = 0; j < 16; ++j) As[mg * 16 + j][ksw] = vals[j];
      }
#pragma unroll
      for (int u = 0; u < 2; ++u) {  // B: Wk or Wv
        int unit = tid + u * 256;
        int row = unit >> 2, cg = unit & 3;
        const void* bsrc = (n0 >= 512) ? Bw2 : Bw;
        size_t nrow = (n0 >= 512) ? (n0 - 512 + row) : (n0 + row);
        ushort_t vals[16];
        rd16(bsrc, nrow * Kdim + k0 + cg * 16, f32, vals);
        *(uint4*)&Bs[row][cg * 16] = *(uint4*)&vals[0];
        *(uint4*)&Bs[row][cg * 16 + 8] = *(uint4*)&vals[8];
      }
      __syncthreads();
#pragma unroll
      for (int kc = 0; kc < 2; ++kc) {
        bf16x8 af[4], bfv[4];
#pragma unroll
        for (int i = 0; i < 4; ++i) {
          int col = (kc * 32 + quad * 8) ^ (8 * (i & 3));
          af[i] = *(const bf16x8*)&As[wm * 64 + i * 16 + l16][col];
          bfv[i] = *(const bf16x8*)&Bs[wn * 64 + i * 16 + l16][kc * 32 + quad * 8];
        }
#pragma unroll
        for (int mt = 0; mt < 4; ++mt)
#pragma unroll
          for (int nt = 0; nt < 4; ++nt)
            acc[mt][nt] = __builtin_amdgcn_mfma_f32_16x16x32_bf16(af[mt], bfv[nt], acc[mt][nt], 0, 0, 0);
      }
    }
    if (n0 < 512) {  // K + RoPE(global)
      const int head = (n0 + wn * 64) >> 6;
#pragma unroll
      for (int mt = 0; mt < 4; ++mt)
#pragma unroll
        for (int r = 0; r < 4; ++r) {
          int pg = m0 + wm * 64 + mt * 16 + quad * 4 + r;
          float x = (float)(pg & 63) * (1.f / 63.f);
          float yy = (float)(pg >> 6) * (1.f / 63.f);
          size_t base = (((size_t)bz * 8 + head) * 4096 + pg) * 64;
#pragma unroll
          for (int j = 0; j < 2; ++j) {
            int c0 = j * 16 + l16;
            float t0 = acc[mt][j][r] + rdE(biasv, head * 64 + c0, f32);
            float t1 = acc[mt][j + 2][r] + rdE(biasv, head * 64 + c0 + 32, f32);
            float fr = __expf((float)c0 * (-9.210340371976184f / 32.f));
            float ax = x * fr, ay = yy * fr;
            outInt[base + c0] = __float2bfloat16(t0 * __cosf(ax) - t1 * __sinf(ax));
            outInt[base + c0 + 32] = __float2bfloat16(t1 * __cosf(ay) + t0 * __sinf(ay));
          }
        }
    } else {  // V -> V^T via LDS-bounce
      const int n0v = n0 - 512;
      __syncthreads();
      ushort_t (*T)[136] = (ushort_t(*)[136]) & smem[0][0][0];
#pragma unroll
      for (int mt = 0; mt < 4; ++mt)
#pragma unroll
        for (int nt = 0; nt < 4; ++nt)
#pragma unroll
          for (int r = 0; r < 4; ++r) {
            int n_l = wn * 64 + nt * 16 + l16;
            int m_l = wm * 64 + mt * 16 + quad * 4 + r;
            T[n_l][m_l] = f2bu(acc[mt][nt][r] + rdE(bias2, n0v + n_l, f32));
          }
      __syncthreads();
      int row = tid >> 1, half = tid & 1;
      size_t gbase = (((size_t)bz * 8 + (n0v >> 6) + (row >> 6)) * 64 + (row & 63)) * 4096 +
                     m0 + half * 64;
      uint4* dst = (uint4*)(outInt2 + gbase);
      const uint4* src = (const uint4*)&T[row][half * 64];
#pragma unroll
      for (int j = 0; j < 8; ++j) dst[j] = src[j];
    }
  } else {
    // ------------------- 64x64 tile path (modes 0/3/4) -------------------
    __shared__ __align__(16) ushort_t As[64][72];
    __shared__ __align__(16) ushort_t Bs[64][72];
    const int m0 = blockIdx.x * 64, n0 = blockIdx.y * 64;

    f32x4 acc[4] = {};
    for (int k0 = 0; k0 < Kdim; k0 += 64) {
      __syncthreads();
      {
        int row = tid >> 2, cg = tid & 3;
        int kg = k0 + cg * 16;
        ushort_t vals[16];
        if constexpr (MODE == 3) {
          if (kg < 512) {
            rd16(Aext, (size_t)(m0 + row) * 512 + kg, f32, vals);
          } else {
            const uint4* p = (const uint4*)(Aint + (size_t)(m0 + row) * 512 + (kg - 512));
            *(uint4*)&vals[0] = p[0]; *(uint4*)&vals[8] = p[1];
          }
        } else if constexpr (MODE == 4) {
          const uint4* p = (const uint4*)(Aint + (size_t)(m0 + row) * 512 + kg);
          *(uint4*)&vals[0] = p[0]; *(uint4*)&vals[8] = p[1];
        } else {
          rd16(Aext, (size_t)(m0 + row) * Kdim + kg, f32, vals);
        }
        *(uint4*)&As[row][cg * 16] = *(uint4*)&vals[0];
        *(uint4*)&As[row][cg * 16 + 8] = *(uint4*)&vals[8];
        ushort_t bv[16];
        rd16(Bw, (size_t)(n0 + row) * Kdim + kg, f32, bv);
        *(uint4*)&Bs[row][cg * 16] = *(uint4*)&bv[0];
        *(uint4*)&Bs[row][cg * 16 + 8] = *(uint4*)&bv[8];
      }
      __syncthreads();
#pragma unroll
      for (int kc = 0; kc < 2; ++kc) {
        bf16x8 af = *(const bf16x8*)&As[w * 16 + l16][kc * 32 + quad * 8];
#pragma unroll
        for (int nt = 0; nt < 4; ++nt) {
          bf16x8 bfv = *(const bf16x8*)&Bs[nt * 16 + l16][kc * 32 + quad * 8];
          acc[nt] = __builtin_amdgcn_mfma_f32_16x16x32_bf16(af, bfv, acc[nt], 0, 0, 0);
        }
      }
    }

    if constexpr (MODE == 0) {
      const int head = n0 >> 6;
#pragma unroll
      for (int r = 0; r < 4; ++r) {
        int mg = m0 + w * 16 + quad * 4 + r;
        int bb = mg >> 10, qi = mg & 1023;
        float x = (float)(qi & 31) * (1.f / 31.f);
        float y = (float)(qi >> 5) * (1.f / 31.f);
        size_t base = (((size_t)bb * 8 + head) * 1024 + qi) * 64;
#pragma unroll
        for (int j = 0; j < 2; ++j) {
          int c0 = j * 16 + l16;
          float t0 = acc[j][r] + rdE(biasv, head * 64 + c0, f32);
          float t1 = acc[j + 2][r] + rdE(biasv, head * 64 + c0 + 32, f32);
          float fr = __expf((float)c0 * (-9.210340371976184f / 32.f));
          float ax = x * fr, ay = y * fr;
          outInt[base + c0] = __float2bfloat16(t0 * __cosf(ax) - t1 * __sinf(ax));
          outInt[base + c0 + 32] = __float2bfloat16(t1 * __cosf(ay) + t0 * __sinf(ay));
        }
      }
    } else if constexpr (MODE == 3) {
#pragma unroll
      for (int r = 0; r < 4; ++r) {
        int mg = m0 + w * 16 + quad * 4 + r;
#pragma unroll
        for (int nt = 0; nt < 4; ++nt) {
          int ng = n0 + nt * 16 + l16;
          size_t idx = (size_t)mg * 512 + ng;
          float g = 1.f / (1.f + __expf(-(acc[nt][r] + rdE(biasv, ng, f32))));
          outInt[idx] = __float2bfloat16(rdE(Aext, idx, f32) + g * b2f(Aint[idx]));
        }
      }
    } else {  // MODE 4
#pragma unroll
      for (int r = 0; r < 4; ++r) {
        int mg = m0 + w * 16 + quad * 4 + r;
#pragma unroll
        for (int nt = 0; nt < 4; ++nt) {
          int ng = n0 + nt * 16 + l16;
          size_t idx = (size_t)mg * 512 + ng;
          float v = acc[nt][r] + rdE(biasv, ng, f32);
          if (f32) ((float*)outExt)[idx] = v;
          else ((BF*)outExt)[idx] = __float2bfloat16(v);
        }
      }
    }
  }
}

// ---------------------------------------------------------------------------
// MFMA flash attention v4: 32 q per wave (two 16-row subtiles), 128 q/block.
// K/V frag reads and staging shared across both q-subtiles -> ~45% less LDS
// traffic per query (the round-6 bottleneck). bh-minor grid (XCD-pinned K/V),
// m=0 softmax with exp2, NS-way key split merged by reduce_k.
// ---------------------------------------------------------------------------
template <int NS>
__global__ __launch_bounds__(256) void attn_k(const BF* __restrict__ Q,
                                              const BF* __restrict__ K,
                                              const BF* __restrict__ VT,
                                              BF* __restrict__ AO,
                                              BF* __restrict__ Opart,
                                              float* __restrict__ lpart) {
  __shared__ __align__(16) ushort_t Ks[64][72];
  __shared__ __align__(16) ushort_t VTs[64][72];
  __shared__ __align__(16) ushort_t Ps[4][32][72];

  const int tid = threadIdx.x;
  const int w = tid >> 6, lane = tid & 63;
  const int quad = lane >> 4, l16 = lane & 15;

  const int g = blockIdx.x;
  const int bh = g & 31;               // XCD = bh % 8
  const int qt = (g >> 5) & 7;         // 8 tiles of 128 q
  const int ks = g >> 8;               // key-split slice
  const int b = bh >> 3, h = bh & 7;
  const int q0 = qt * 128 + w * 32;
  const int kspan = 4096 / NS, kbase = ks * kspan;

  bf16x8 qa[2][2];
#pragma unroll
  for (int qs = 0; qs < 2; ++qs) {
    const BF* qp = Q + (((size_t)bh << 10) + q0 + qs * 16 + l16) * 64 + quad * 8;
#pragma unroll
    for (int hh = 0; hh < 2; ++hh) {
      bf16x8 t = *(const bf16x8*)(qp + 32 * hh);
#pragma unroll
      for (int j = 0; j < 8; ++j) t[j] = (__bf16)(0.1803368801111f * (float)t[j]);
      qa[qs][hh] = t;  // scale = (1/8)*log2(e); p = exp2(s)
    }
  }

  const BF* Kp = K + (size_t)bh * 4096 * 64;    // [key][dh]
  const BF* VTp = VT + (size_t)bh * 64 * 4096;  // [dh][key]

  f32x4 o[2][4] = {};
  float lp[2][4] = {};

  const int srow = tid >> 2, scol = (tid & 3) * 16;
  {  // stage first chunk
    const uint4* kp = (const uint4*)(Kp + (size_t)(kbase + srow) * 64 + scol);
    const uint4* vp = (const uint4*)(VTp + (size_t)srow * 4096 + kbase + scol);
    uint4 a = kp[0], bb = kp[1], c = vp[0], d = vp[1];
    *(uint4*)&Ks[srow][scol] = a;  *(uint4*)&Ks[srow][scol + 8] = bb;
    *(uint4*)&VTs[srow][scol] = c; *(uint4*)&VTs[srow][scol + 8] = d;
  }

  for (int c0 = kbase; c0 < kbase + kspan; c0 += 64) {
    __syncthreads();
    uint4 nk0, nk1, nv0, nv1;
    const bool more = (c0 + 64 < kbase + kspan);
    if (more) {
      const uint4* kp = (const uint4*)(Kp + (size_t)(c0 + 64 + srow) * 64 + scol);
      const uint4* vp = (const uint4*)(VTp + (size_t)srow * 4096 + c0 + 64 + scol);
      nk0 = kp[0]; nk1 = kp[1]; nv0 = vp[0]; nv1 = vp[1];
    }

    // ---- S = Qs K^T ; P = exp2(S); write P to per-wave LDS ----
#pragma unroll
    for (int ct = 0; ct < 4; ++ct) {
      bf16x8 kb0 = *(const bf16x8*)&Ks[ct * 16 + l16][quad * 8];
      bf16x8 kb1 = *(const bf16x8*)&Ks[ct * 16 + l16][32 + quad * 8];
#pragma unroll
      for (int qs = 0; qs < 2; ++qs) {
        f32x4 s = {};
        s = __builtin_amdgcn_mfma_f32_16x16x32_bf16(qa[qs][0], kb0, s, 0, 0, 0);
        s = __builtin_amdgcn_mfma_f32_16x16x32_bf16(qa[qs][1], kb1, s, 0, 0, 0);
#pragma unroll
        for (int r = 0; r < 4; ++r) {
          float p = __builtin_exp2f(s[r]);
          lp[qs][r] += p;
          Ps[w][qs * 16 + quad * 4 + r][ct * 16 + l16] = f2bu(p);
        }
      }
    }

    // ---- read P in A-layout; O += P V ----
    bf16x8 pa[2][2];
#pragma unroll
    for (int qs = 0; qs < 2; ++qs) {
      pa[qs][0] = *(const bf16x8*)&Ps[w][qs * 16 + l16][quad * 8];
      pa[qs][1] = *(const bf16x8*)&Ps[w][qs * 16 + l16][32 + quad * 8];
    }
#pragma unroll
    for (int nt = 0; nt < 4; ++nt) {
      bf16x8 vb0 = *(const bf16x8*)&VTs[nt * 16 + l16][quad * 8];
      bf16x8 vb1 = *(const bf16x8*)&VTs[nt * 16 + l16][32 + quad * 8];
#pragma unroll
      for (int qs = 0; qs < 2; ++qs) {
        o[qs][nt] = __builtin_amdgcn_mfma_f32_16x16x32_bf16(pa[qs][0], vb0, o[qs][nt], 0, 0, 0);
        o[qs][nt] = __builtin_amdgcn_mfma_f32_16x16x32_bf16(pa[qs][1], vb1, o[qs][nt], 0, 0, 0);
      }
    }

    __syncthreads();
    if (more) {
      *(uint4*)&Ks[srow][scol] = nk0;  *(uint4*)&Ks[srow][scol + 8] = nk1;
      *(uint4*)&VTs[srow][scol] = nv0; *(uint4*)&VTs[srow][scol + 8] = nv1;
    }
  }

#pragma unroll
  for (int qs = 0; qs < 2; ++qs) {
    float invl[4];
#pragma unroll
    for (int r = 0; r < 4; ++r) {
      float v = lp[qs][r];
#pragma unroll
      for (int d = 1; d < 16; d <<= 1) v += __shfl_xor(v, d);
      if (NS == 1) invl[r] = 1.f / v;
      else if (l16 == 0)
        lpart[ks * 32768 + (bh << 10) + q0 + qs * 16 + quad * 4 + r] = v;
    }
#pragma unroll
    for (int nt = 0; nt < 4; ++nt)
#pragma unroll
      for (int r = 0; r < 4; ++r) {
        int qg = q0 + qs * 16 + quad * 4 + r;
        if (NS == 1) {
          AO[(((size_t)b << 10) + qg) * 512 + h * 64 + nt * 16 + l16] =
              __float2bfloat16(o[qs][nt][r] * invl[r]);
        } else {
          Opart[(size_t)ks * 2097152 + (((size_t)bh << 10) + qg) * 64 + nt * 16 + l16] =
              __float2bfloat16(o[qs][nt][r]);
        }
      }
  }
}

// Merge NS K-split slices: AO = (sum O_s) / (sum l_s).
template <int NS>
__global__ __launch_bounds__(256) void reduce_k(const BF* __restrict__ Opart,
                                                const float* __restrict__ lpart,
                                                BF* __restrict__ AO) {
  int e0 = (blockIdx.x * 256 + threadIdx.x) * 4;
  int row = e0 >> 6, col = e0 & 63;  // row = (bh<<10)+q
  float lsum = 0.f;
#pragma unroll
  for (int s = 0; s < NS; ++s) lsum += lpart[s * 32768 + row];
  float inv = 1.f / lsum;
  float acc[4] = {};
#pragma unroll
  for (int s = 0; s < NS; ++s) {
    uint2 u = *(const uint2*)((const ushort_t*)Opart + (size_t)s * 2097152 +
                              (size_t)row * 64 + col);
    const ushort_t* pu = (const ushort_t*)&u;
#pragma unroll
    for (int j = 0; j < 4; ++j)
      acc[j] += __uint_as_float((unsigned)pu[j] << 16);
  }
  ushort_t outv[4];
#pragma unroll
  for (int j = 0; j < 4; ++j) outv[j] = f2bu(acc[j] * inv);
  int bh = row >> 10, q = row & 1023, bb = bh >> 3, h = bh & 7;
  *(uint2*)(AO + (((size_t)bb << 10) + q) * 512 + h * 64 + col) = *(uint2*)outv;
}

extern "C" void kernel_launch(void* const* d_in, const int* in_sizes, int n_in,
                              void* d_out, int out_size, void* d_ws, size_t ws_size,
                              hipStream_t stream) {
  const void* local = d_in[0];
  const void* gfeat = d_in[1];
  const void* Wq = d_in[2];
  const void* bq = d_in[3];
  const void* Wk = d_in[4];
  const void* bk = d_in[5];
  const void* Wv = d_in[6];
  const void* bv = d_in[7];
  const void* Wg = d_in[8];
  const void* bg = d_in[9];
  const void* Wo = d_in[10];
  const void* bo = d_in[11];

  char* w = (char*)d_ws;
  int* flag = (int*)w;        w += 256;
  BF* Qb = (BF*)w;            w += (size_t)2097152 * 2;  // 4 MB (reused as ENH)
  BF* Kb = (BF*)w;            w += (size_t)8388608 * 2;  // 16 MB
  BF* VTb = (BF*)w;           w += (size_t)8388608 * 2;  // 16 MB (V^T: [b,h,dh,key])
  BF* AO = (BF*)w;            w += (size_t)2097152 * 2;  // 4 MB
  BF* Opart = (BF*)w;                                     // NS x 4 MB
  size_t baseOff = (size_t)(w - (char*)d_ws);
  BF* ENH = Qb;

  int NS = 1;
  if (baseOff + 4 * (4194304 + 131072) <= ws_size) NS = 4;
  else if (baseOff + 2 * (4194304 + 131072) <= ws_size) NS = 2;
  float* lpart = (float*)(w + (size_t)NS * 4194304);

  dim3 blk(256);
  detect_k<<<dim3(1), blk, 0, stream>>>((const unsigned short*)local, flag);
  mgemm_k<0><<<dim3(64, 8, 1), blk, 0, stream>>>(local, nullptr, Wq, nullptr, bq, nullptr, Qb, nullptr, nullptr, 512, flag);
  mgemm_k<5><<<dim3(1024, 1, 1), blk, 0, stream>>>(gfeat, nullptr, Wk, Wv, bk, bv, Kb, VTb, nullptr, 512, flag);
  if (NS == 4) {
    attn_k<4><<<dim3(1024), blk, 0, stream>>>(Qb, Kb, VTb, AO, Opart, lpart);
    reduce_k<4><<<dim3(2048), blk, 0, stream>>>(Opart, lpart, AO);
  } else if (NS == 2) {
    attn_k<2><<<dim3(512), blk, 0, stream>>>(Qb, Kb, VTb, AO, Opart, lpart);
    reduce_k<2><<<dim3(2048), blk, 0, stream>>>(Opart, lpart, AO);
  } else {
    attn_k<1><<<dim3(256), blk, 0, stream>>>(Qb, Kb, VTb, AO, nullptr, nullptr);
  }
  mgemm_k<3><<<dim3(64, 8, 1), blk, 0, stream>>>(local, AO, Wg, nullptr, bg, nullptr, ENH, nullptr, nullptr, 1024, flag);
  mgemm_k<4><<<dim3(64, 8, 1), blk, 0, stream>>>(nullptr, ENH, Wo, nullptr, bo, nullptr, nullptr, nullptr, d_out, 512, flag);
}

// Round 8
// 281.585 us; speedup vs baseline: 1.2325x; 1.0430x over previous
//
#include <hip/hip_runtime.h>
#include <hip/hip_bf16.h>
#include <cstdint>

typedef __hip_bfloat16 BF;
typedef unsigned short ushort_t;
typedef __attribute__((ext_vector_type(8))) __bf16 bf16x8;
typedef __attribute__((ext_vector_type(4))) float f32x4;

__device__ __forceinline__ float b2f(BF x) { return __bfloat162float(x); }
__device__ __forceinline__ unsigned short f2bu(float f) {
  union { BF b; unsigned short u; } c; c.b = __float2bfloat16(f); return c.u;
}
__device__ __forceinline__ float rdE(const void* p, size_t i, bool f32) {
  return f32 ? ((const float*)p)[i] : __bfloat162float(((const BF*)p)[i]);
}
// Read 16 consecutive external elements as bf16 bit patterns.
__device__ __forceinline__ void rd16(const void* p, size_t i, bool f32, ushort_t* out) {
  if (f32) {
    const float* fp = (const float*)p + i;
#pragma unroll
    for (int j = 0; j < 16; j += 4) {
      float4 v = *(const float4*)(fp + j);
      out[j] = f2bu(v.x); out[j + 1] = f2bu(v.y);
      out[j + 2] = f2bu(v.z); out[j + 3] = f2bu(v.w);
    }
  } else {
    const uint4* up = (const uint4*)((const BF*)p + i);
    *(uint4*)&out[0] = up[0];
    *(uint4*)&out[8] = up[1];
  }
}

// Detect input dtype (fp32 vs bf16) from bit patterns; see round-1 notes.
__global__ void detect_k(const unsigned short* __restrict__ x, int* __restrict__ flag) {
  __shared__ int cnt;
  if (threadIdx.x == 0) cnt = 0;
  __syncthreads();
  int c = 0;
  for (int i = threadIdx.x; i < 4096; i += 256) {
    int e = (x[i] >> 7) & 0xFF;
    if (e >= 0x86) c++;
  }
  if (c) atomicAdd(&cnt, c);
  __syncthreads();
  if (threadIdx.x == 0) *flag = (cnt > 64) ? 1 : 0;
}

// One-time transpose+convert: gfeat [bz][k=512][m=4096] (fp32/bf16) ->
// gfT [bz][m][k] bf16 row-major. Kills mode5's 8x-redundant in-LDS transpose.
__global__ __launch_bounds__(256) void prep_k(const void* __restrict__ gfeat,
                                              BF* __restrict__ gfT,
                                              const int* __restrict__ flagp) {
  const bool f32 = (*flagp != 0);
  __shared__ __align__(16) ushort_t T[64][72];
  const int g = blockIdx.x;  // 4 bz x 64 mt x 8 kt = 2048
  const int bz = g & 3, mt = (g >> 2) & 63, kt = g >> 8;
  const int t = threadIdx.x;
  {
    int krow = t >> 2, mg = t & 3;
    ushort_t vals[16];
    rd16(gfeat,
         (size_t)bz * 512 * 4096 + (size_t)(kt * 64 + krow) * 4096 + mt * 64 + mg * 16,
         f32, vals);
#pragma unroll
    for (int j = 0; j < 16; ++j) T[mg * 16 + j][krow] = vals[j];
  }
  __syncthreads();
  int mrow = t >> 2, kg = t & 3;
  uint4 a = *(const uint4*)&T[mrow][kg * 16];
  uint4 b = *(const uint4*)&T[mrow][kg * 16 + 8];
  size_t o = ((size_t)bz * 4096 + mt * 64 + mrow) * 512 + kt * 64 + kg * 16;
  *(uint4*)&gfT[o] = a;
  *(uint4*)&gfT[o + 8] = b;
}

// ---------------------------------------------------------------------------
// MFMA GEMM, C = A @ B^T (+bias epilogues).
// MODE 0: Q proj, 64x64 tile; epilogue = RoPE(local) * QS (QS=log2e/8 folded
//         so attention uses exp2 directly).
// MODE 5: fused K/V proj from pre-transposed bf16 gfT; 128x128, 1D XCD grid.
// MODE 3/4: gate / out, 64x64 tiles.
// ---------------------------------------------------------------------------
#define QS 0.1803368801111f
template <int MODE>
__global__ __launch_bounds__(256) void mgemm_k(
    const void* __restrict__ Aext, const BF* __restrict__ Aint,
    const void* __restrict__ Bw, const void* __restrict__ Bw2,
    const void* __restrict__ biasv, const void* __restrict__ bias2,
    BF* __restrict__ outInt, BF* __restrict__ outInt2,
    void* __restrict__ outExt, int Kdim, const int* __restrict__ flagp) {
  const bool f32 = (*flagp != 0);
  const int tid = threadIdx.x;
  const int w = tid >> 6, lane = tid & 63;
  const int quad = lane >> 4, l16 = lane & 15;

  if constexpr (MODE == 5) {
    __shared__ __align__(16) ushort_t smem[2][128][72];
    auto As = smem[0];
    auto Bs = smem[1];
    const int wm = w >> 1, wn = w & 1;
    const int g = blockIdx.x;
    const int a = g & 7, y = (g >> 3) & 7, bidx = g >> 6;
    const int m0 = ((bidx << 1) | (a & 1)) * 128;
    const int n0 = y * 128;
    const int bz = a >> 1;

    f32x4 acc[4][4] = {};
    for (int k0 = 0; k0 < Kdim; k0 += 64) {
      __syncthreads();
#pragma unroll
      for (int u = 0; u < 2; ++u) {  // A: bf16 row-major gfT, pure b128
        int unit = tid + u * 256;
        int row = unit >> 2, cg = unit & 3;
        const uint4* p = (const uint4*)(Aint + ((size_t)bz * 4096 + m0 + row) * 512 +
                                        k0 + cg * 16);
        *(uint4*)&As[row][cg * 16] = p[0];
        *(uint4*)&As[row][cg * 16 + 8] = p[1];
      }
#pragma unroll
      for (int u = 0; u < 2; ++u) {  // B: Wk or Wv
        int unit = tid + u * 256;
        int row = unit >> 2, cg = unit & 3;
        const void* bsrc = (n0 >= 512) ? Bw2 : Bw;
        size_t nrow = (n0 >= 512) ? (n0 - 512 + row) : (n0 + row);
        ushort_t vals[16];
        rd16(bsrc, nrow * Kdim + k0 + cg * 16, f32, vals);
        *(uint4*)&Bs[row][cg * 16] = *(uint4*)&vals[0];
        *(uint4*)&Bs[row][cg * 16 + 8] = *(uint4*)&vals[8];
      }
      __syncthreads();
#pragma unroll
      for (int kc = 0; kc < 2; ++kc) {
        bf16x8 af[4], bfv[4];
#pragma unroll
        for (int i = 0; i < 4; ++i) {
          af[i] = *(const bf16x8*)&As[wm * 64 + i * 16 + l16][kc * 32 + quad * 8];
          bfv[i] = *(const bf16x8*)&Bs[wn * 64 + i * 16 + l16][kc * 32 + quad * 8];
        }
#pragma unroll
        for (int mt = 0; mt < 4; ++mt)
#pragma unroll
          for (int nt = 0; nt < 4; ++nt)
            acc[mt][nt] = __builtin_amdgcn_mfma_f32_16x16x32_bf16(af[mt], bfv[nt], acc[mt][nt], 0, 0, 0);
      }
    }
    if (n0 < 512) {  // K + RoPE(global)
      const int head = (n0 + wn * 64) >> 6;
#pragma unroll
      for (int mt = 0; mt < 4; ++mt)
#pragma unroll
        for (int r = 0; r < 4; ++r) {
          int pg = m0 + wm * 64 + mt * 16 + quad * 4 + r;
          float x = (float)(pg & 63) * (1.f / 63.f);
          float yy = (float)(pg >> 6) * (1.f / 63.f);
          size_t base = (((size_t)bz * 8 + head) * 4096 + pg) * 64;
#pragma unroll
          for (int j = 0; j < 2; ++j) {
            int c0 = j * 16 + l16;
            float t0 = acc[mt][j][r] + rdE(biasv, head * 64 + c0, f32);
            float t1 = acc[mt][j + 2][r] + rdE(biasv, head * 64 + c0 + 32, f32);
            float fr = __expf((float)c0 * (-9.210340371976184f / 32.f));
            float ax = x * fr, ay = yy * fr;
            outInt[base + c0] = __float2bfloat16(t0 * __cosf(ax) - t1 * __sinf(ax));
            outInt[base + c0 + 32] = __float2bfloat16(t1 * __cosf(ay) + t0 * __sinf(ay));
          }
        }
    } else {  // V -> V^T via LDS-bounce
      const int n0v = n0 - 512;
      __syncthreads();
      ushort_t (*T)[136] = (ushort_t(*)[136]) & smem[0][0][0];
#pragma unroll
      for (int mt = 0; mt < 4; ++mt)
#pragma unroll
        for (int nt = 0; nt < 4; ++nt)
#pragma unroll
          for (int r = 0; r < 4; ++r) {
            int n_l = wn * 64 + nt * 16 + l16;
            int m_l = wm * 64 + mt * 16 + quad * 4 + r;
            T[n_l][m_l] = f2bu(acc[mt][nt][r] + rdE(bias2, n0v + n_l, f32));
          }
      __syncthreads();
      int row = tid >> 1, half = tid & 1;
      size_t gbase = (((size_t)bz * 8 + (n0v >> 6) + (row >> 6)) * 64 + (row & 63)) * 4096 +
                     m0 + half * 64;
      uint4* dst = (uint4*)(outInt2 + gbase);
      const uint4* src = (const uint4*)&T[row][half * 64];
#pragma unroll
      for (int j = 0; j < 8; ++j) dst[j] = src[j];
    }
  } else {
    // ------------------- 64x64 tile path (modes 0/3/4) -------------------
    __shared__ __align__(16) ushort_t As[64][72];
    __shared__ __align__(16) ushort_t Bs[64][72];
    const int m0 = blockIdx.x * 64, n0 = blockIdx.y * 64;

    f32x4 acc[4] = {};
    for (int k0 = 0; k0 < Kdim; k0 += 64) {
      __syncthreads();
      {
        int row = tid >> 2, cg = tid & 3;
        int kg = k0 + cg * 16;
        ushort_t vals[16];
        if constexpr (MODE == 3) {
          if (kg < 512) {
            rd16(Aext, (size_t)(m0 + row) * 512 + kg, f32, vals);
          } else {
            const uint4* p = (const uint4*)(Aint + (size_t)(m0 + row) * 512 + (kg - 512));
            *(uint4*)&vals[0] = p[0]; *(uint4*)&vals[8] = p[1];
          }
        } else if constexpr (MODE == 4) {
          const uint4* p = (const uint4*)(Aint + (size_t)(m0 + row) * 512 + kg);
          *(uint4*)&vals[0] = p[0]; *(uint4*)&vals[8] = p[1];
        } else {
          rd16(Aext, (size_t)(m0 + row) * Kdim + kg, f32, vals);
        }
        *(uint4*)&As[row][cg * 16] = *(uint4*)&vals[0];
        *(uint4*)&As[row][cg * 16 + 8] = *(uint4*)&vals[8];
        ushort_t bv[16];
        rd16(Bw, (size_t)(n0 + row) * Kdim + kg, f32, bv);
        *(uint4*)&Bs[row][cg * 16] = *(uint4*)&bv[0];
        *(uint4*)&Bs[row][cg * 16 + 8] = *(uint4*)&bv[8];
      }
      __syncthreads();
#pragma unroll
      for (int kc = 0; kc < 2; ++kc) {
        bf16x8 af = *(const bf16x8*)&As[w * 16 + l16][kc * 32 + quad * 8];
#pragma unroll
        for (int nt = 0; nt < 4; ++nt) {
          bf16x8 bfv = *(const bf16x8*)&Bs[nt * 16 + l16][kc * 32 + quad * 8];
          acc[nt] = __builtin_amdgcn_mfma_f32_16x16x32_bf16(af, bfv, acc[nt], 0, 0, 0);
        }
      }
    }

    if constexpr (MODE == 0) {
      const int head = n0 >> 6;
#pragma unroll
      for (int r = 0; r < 4; ++r) {
        int mg = m0 + w * 16 + quad * 4 + r;
        int bb = mg >> 10, qi = mg & 1023;
        float x = (float)(qi & 31) * (1.f / 31.f);
        float y = (float)(qi >> 5) * (1.f / 31.f);
        size_t base = (((size_t)bb * 8 + head) * 1024 + qi) * 64;
#pragma unroll
        for (int j = 0; j < 2; ++j) {
          int c0 = j * 16 + l16;
          float t0 = acc[j][r] + rdE(biasv, head * 64 + c0, f32);
          float t1 = acc[j + 2][r] + rdE(biasv, head * 64 + c0 + 32, f32);
          float fr = __expf((float)c0 * (-9.210340371976184f / 32.f));
          float ax = x * fr, ay = y * fr;
          outInt[base + c0] = __float2bfloat16((t0 * __cosf(ax) - t1 * __sinf(ax)) * QS);
          outInt[base + c0 + 32] = __float2bfloat16((t1 * __cosf(ay) + t0 * __sinf(ay)) * QS);
        }
      }
    } else if constexpr (MODE == 3) {
#pragma unroll
      for (int r = 0; r < 4; ++r) {
        int mg = m0 + w * 16 + quad * 4 + r;
#pragma unroll
        for (int nt = 0; nt < 4; ++nt) {
          int ng = n0 + nt * 16 + l16;
          size_t idx = (size_t)mg * 512 + ng;
          float g = 1.f / (1.f + __expf(-(acc[nt][r] + rdE(biasv, ng, f32))));
          outInt[idx] = __float2bfloat16(rdE(Aext, idx, f32) + g * b2f(Aint[idx]));
        }
      }
    } else {  // MODE 4
#pragma unroll
      for (int r = 0; r < 4; ++r) {
        int mg = m0 + w * 16 + quad * 4 + r;
#pragma unroll
        for (int nt = 0; nt < 4; ++nt) {
          int ng = n0 + nt * 16 + l16;
          size_t idx = (size_t)mg * 512 + ng;
          float v = acc[nt][r] + rdE(biasv, ng, f32);
          if (f32) ((float*)outExt)[idx] = v;
          else ((BF*)outExt)[idx] = __float2bfloat16(v);
        }
      }
    }
  }
}

// ---------------------------------------------------------------------------
// MFMA flash attention v5 — transposed algebra.
// B-frag of X^T uses the same LDS read as A-frag of X, so:
//   S^T = mfma(kb, qa)  (same loads as before, args swapped) -> rows=keys
//   => P values land on 4 consecutive cols of P[q][key] -> ds_write_b64 (8
//      writes/chunk, conflict-free) instead of 32 conflicted b16 writes.
//   O^T = mfma(vb, pa); l = mfma(ones, pa) (rows of D all = row-sum) kills
//      32 VALU adds + tail shuffles. Epilogue: 4 consecutive dh -> b64 store.
// Q pre-scaled by log2e/8 in mode0 -> exp2 directly.
// ---------------------------------------------------------------------------
template <int NS>
__global__ __launch_bounds__(256) void attn_k(const BF* __restrict__ Q,
                                              const BF* __restrict__ K,
                                              const BF* __restrict__ VT,
                                              BF* __restrict__ AO,
                                              BF* __restrict__ Opart,
                                              float* __restrict__ lpart) {
  __shared__ __align__(16) ushort_t Ks[64][72];
  __shared__ __align__(16) ushort_t VTs[64][72];
  __shared__ __align__(16) ushort_t Ps[4][32][72];

  const int tid = threadIdx.x;
  const int w = tid >> 6, lane = tid & 63;
  const int quad = lane >> 4, l16 = lane & 15;

  const int g = blockIdx.x;
  const int bh = g & 31;               // XCD = bh % 8
  const int qt = (g >> 5) & 7;
  const int ks = g >> 8;
  const int b = bh >> 3, h = bh & 7;
  const int q0 = qt * 128 + w * 32;
  const int kspan = 4096 / NS, kbase = ks * kspan;

  bf16x8 qa[2][2];
#pragma unroll
  for (int qs = 0; qs < 2; ++qs) {
    const BF* qp = Q + (((size_t)bh << 10) + q0 + qs * 16 + l16) * 64 + quad * 8;
    qa[qs][0] = *(const bf16x8*)qp;
    qa[qs][1] = *(const bf16x8*)(qp + 32);
  }
  bf16x8 ones;
#pragma unroll
  for (int j = 0; j < 8; ++j) ones[j] = (__bf16)1.0f;

  const BF* Kp = K + (size_t)bh * 4096 * 64;    // [key][dh]
  const BF* VTp = VT + (size_t)bh * 64 * 4096;  // [dh][key]

  f32x4 o[2][4] = {};
  f32x4 ol[2] = {};

  const int srow = tid >> 2, scol = (tid & 3) * 16;
  {  // stage first chunk
    const uint4* kp = (const uint4*)(Kp + (size_t)(kbase + srow) * 64 + scol);
    const uint4* vp = (const uint4*)(VTp + (size_t)srow * 4096 + kbase + scol);
    uint4 a = kp[0], bb = kp[1], c = vp[0], d = vp[1];
    *(uint4*)&Ks[srow][scol] = a;  *(uint4*)&Ks[srow][scol + 8] = bb;
    *(uint4*)&VTs[srow][scol] = c; *(uint4*)&VTs[srow][scol + 8] = d;
  }

  for (int c0 = kbase; c0 < kbase + kspan; c0 += 64) {
    __syncthreads();
    uint4 nk0, nk1, nv0, nv1;
    const bool more = (c0 + 64 < kbase + kspan);
    if (more) {
      const uint4* kp = (const uint4*)(Kp + (size_t)(c0 + 64 + srow) * 64 + scol);
      const uint4* vp = (const uint4*)(VTp + (size_t)srow * 4096 + c0 + 64 + scol);
      nk0 = kp[0]; nk1 = kp[1]; nv0 = vp[0]; nv1 = vp[1];
    }

    // ---- S^T = K Q^T per 16-key subtile; P[q][key] <- exp2, b64 writes ----
#pragma unroll
    for (int ct = 0; ct < 4; ++ct) {
      bf16x8 kb0 = *(const bf16x8*)&Ks[ct * 16 + l16][quad * 8];
      bf16x8 kb1 = *(const bf16x8*)&Ks[ct * 16 + l16][32 + quad * 8];
#pragma unroll
      for (int qs = 0; qs < 2; ++qs) {
        f32x4 s = {};
        s = __builtin_amdgcn_mfma_f32_16x16x32_bf16(kb0, qa[qs][0], s, 0, 0, 0);
        s = __builtin_amdgcn_mfma_f32_16x16x32_bf16(kb1, qa[qs][1], s, 0, 0, 0);
        ushort_t pv[4];
#pragma unroll
        for (int r = 0; r < 4; ++r) pv[r] = f2bu(__builtin_exp2f(s[r]));
        *(uint2*)&Ps[w][qs * 16 + l16][ct * 16 + quad * 4] = *(uint2*)pv;
      }
    }

    // ---- O^T += V^T P^T ; l += 1^T P^T (ones-MFMA row sums) ----
#pragma unroll
    for (int qs = 0; qs < 2; ++qs) {
      bf16x8 pa0 = *(const bf16x8*)&Ps[w][qs * 16 + l16][quad * 8];
      bf16x8 pa1 = *(const bf16x8*)&Ps[w][qs * 16 + l16][32 + quad * 8];
      ol[qs] = __builtin_amdgcn_mfma_f32_16x16x32_bf16(ones, pa0, ol[qs], 0, 0, 0);
      ol[qs] = __builtin_amdgcn_mfma_f32_16x16x32_bf16(ones, pa1, ol[qs], 0, 0, 0);
#pragma unroll
      for (int nt = 0; nt < 4; ++nt) {
        bf16x8 vb0 = *(const bf16x8*)&VTs[nt * 16 + l16][quad * 8];
        bf16x8 vb1 = *(const bf16x8*)&VTs[nt * 16 + l16][32 + quad * 8];
        o[qs][nt] = __builtin_amdgcn_mfma_f32_16x16x32_bf16(vb0, pa0, o[qs][nt], 0, 0, 0);
        o[qs][nt] = __builtin_amdgcn_mfma_f32_16x16x32_bf16(vb1, pa1, o[qs][nt], 0, 0, 0);
      }
    }

    __syncthreads();
    if (more) {
      *(uint4*)&Ks[srow][scol] = nk0;  *(uint4*)&Ks[srow][scol + 8] = nk1;
      *(uint4*)&VTs[srow][scol] = nv0; *(uint4*)&VTs[srow][scol + 8] = nv1;
    }
  }

  // ---- epilogue: lane holds O^T[dh = nt*16+quad*4+r][q = l16] ----
#pragma unroll
  for (int qs = 0; qs < 2; ++qs) {
    int qg = q0 + qs * 16 + l16;
    if (NS == 1) {
      float invl = 1.f / ol[qs][0];
#pragma unroll
      for (int nt = 0; nt < 4; ++nt) {
        ushort_t ov[4];
#pragma unroll
        for (int r = 0; r < 4; ++r) ov[r] = f2bu(o[qs][nt][r] * invl);
        *(uint2*)(AO + (((size_t)b << 10) + qg) * 512 + h * 64 + nt * 16 + quad * 4) =
            *(uint2*)ov;
      }
    } else {
      if (quad == 0) lpart[ks * 32768 + (bh << 10) + qg] = ol[qs][0];
#pragma unroll
      for (int nt = 0; nt < 4; ++nt) {
        ushort_t ov[4];
#pragma unroll
        for (int r = 0; r < 4; ++r) ov[r] = f2bu(o[qs][nt][r]);
        *(uint2*)(Opart + (size_t)ks * 2097152 + (((size_t)bh << 10) + qg) * 64 +
                  nt * 16 + quad * 4) = *(uint2*)ov;
      }
    }
  }
}

// Merge NS K-split slices: AO = (sum O_s) / (sum l_s).
template <int NS>
__global__ __launch_bounds__(256) void reduce_k(const BF* __restrict__ Opart,
                                                const float* __restrict__ lpart,
                                                BF* __restrict__ AO) {
  int e0 = (blockIdx.x * 256 + threadIdx.x) * 4;
  int row = e0 >> 6, col = e0 & 63;  // row = (bh<<10)+q
  float lsum = 0.f;
#pragma unroll
  for (int s = 0; s < NS; ++s) lsum += lpart[s * 32768 + row];
  float inv = 1.f / lsum;
  float acc[4] = {};
#pragma unroll
  for (int s = 0; s < NS; ++s) {
    uint2 u = *(const uint2*)((const ushort_t*)Opart + (size_t)s * 2097152 +
                              (size_t)row * 64 + col);
    const ushort_t* pu = (const ushort_t*)&u;
#pragma unroll
    for (int j = 0; j < 4; ++j)
      acc[j] += __uint_as_float((unsigned)pu[j] << 16);
  }
  ushort_t outv[4];
#pragma unroll
  for (int j = 0; j < 4; ++j) outv[j] = f2bu(acc[j] * inv);
  int bh = row >> 10, q = row & 1023, bb = bh >> 3, h = bh & 7;
  *(uint2*)(AO + (((size_t)bb << 10) + q) * 512 + h * 64 + col) = *(uint2*)outv;
}

extern "C" void kernel_launch(void* const* d_in, const int* in_sizes, int n_in,
                              void* d_out, int out_size, void* d_ws, size_t ws_size,
                              hipStream_t stream) {
  const void* local = d_in[0];
  const void* gfeat = d_in[1];
  const void* Wq = d_in[2];
  const void* bq = d_in[3];
  const void* Wk = d_in[4];
  const void* bk = d_in[5];
  const void* Wv = d_in[6];
  const void* bv = d_in[7];
  const void* Wg = d_in[8];
  const void* bg = d_in[9];
  const void* Wo = d_in[10];
  const void* bo = d_in[11];

  char* w = (char*)d_ws;
  int* flag = (int*)w;        w += 256;
  BF* Qb = (BF*)w;            w += (size_t)2097152 * 2;  // 4 MB (reused as ENH)
  BF* Kb = (BF*)w;            w += (size_t)8388608 * 2;  // 16 MB
  BF* VTb = (BF*)w;           w += (size_t)8388608 * 2;  // 16 MB (V^T: [b,h,dh,key])
  BF* AO = (BF*)w;            w += (size_t)2097152 * 2;  // 4 MB
  // Region X: first gfT (16.75 MB, dead after mode5), then Opart+lpart.
  BF* gfT = (BF*)w;
  BF* Opart = (BF*)w;
  size_t baseOff = (size_t)(w - (char*)d_ws);
  BF* ENH = Qb;

  int NS = 1;
  if (baseOff + 4 * (4194304 + 131072) <= ws_size) NS = 4;
  else if (baseOff + 16777216 + 2 * 131072 <= ws_size) NS = 2;
  float* lpart = (float*)(w + (size_t)NS * 4194304);

  dim3 blk(256);
  detect_k<<<dim3(1), blk, 0, stream>>>((const unsigned short*)local, flag);
  prep_k<<<dim3(2048), blk, 0, stream>>>(gfeat, gfT, flag);
  mgemm_k<0><<<dim3(64, 8, 1), blk, 0, stream>>>(local, nullptr, Wq, nullptr, bq, nullptr, Qb, nullptr, nullptr, 512, flag);
  mgemm_k<5><<<dim3(1024, 1, 1), blk, 0, stream>>>(nullptr, gfT, Wk, Wv, bk, bv, Kb, VTb, nullptr, 512, flag);
  if (NS == 4) {
    attn_k<4><<<dim3(1024), blk, 0, stream>>>(Qb, Kb, VTb, AO, Opart, lpart);
    reduce_k<4><<<dim3(2048), blk, 0, stream>>>(Opart, lpart, AO);
  } else if (NS == 2) {
    attn_k<2><<<dim3(512), blk, 0, stream>>>(Qb, Kb, VTb, AO, Opart, lpart);
    reduce_k<2><<<dim3(2048), blk, 0, stream>>>(Opart, lpart, AO);
  } else {
    attn_k<1><<<dim3(256), blk, 0, stream>>>(Qb, Kb, VTb, AO, nullptr, nullptr);
  }
  mgemm_k<3><<<dim3(64, 8, 1), blk, 0, stream>>>(local, AO, Wg, nullptr, bg, nullptr, ENH, nullptr, nullptr, 1024, flag);
  mgemm_k<4><<<dim3(64, 8, 1), blk, 0, stream>>>(nullptr, ENH, Wo, nullptr, bo, nullptr, nullptr, nullptr, d_out, 512, flag);
}